// Round 1
// baseline (1587.720 us; speedup 1.0000x reference)
//
#include <hip/hip_runtime.h>

#define HIDDEN 64

// ---------- degree counting ----------
__global__ void degree_kernel(const int* __restrict__ src, const int* __restrict__ dst,
                              float* __restrict__ outdeg, float* __restrict__ indeg, int E) {
    int i = blockIdx.x * blockDim.x + threadIdx.x;
    int stride = gridDim.x * blockDim.x;
    for (; i < E; i += stride) {
        atomicAdd(&outdeg[src[i]], 1.0f);
        atomicAdd(&indeg[dst[i]], 1.0f);
    }
}

// deg -> deg^{-1/2} with clamp-to-1, in place
__global__ void norm_kernel(float* __restrict__ dsrc, float* __restrict__ ddst, int N) {
    int i = blockIdx.x * blockDim.x + threadIdx.x;
    if (i < N) {
        dsrc[i] = rsqrtf(fmaxf(dsrc[i], 1.0f));
        ddst[i] = rsqrtf(fmaxf(ddst[i], 1.0f));
    }
}

// ---------- embedding gather: h[n][d] = emb[feats[n]][d] ----------
__global__ void embed_kernel(const int* __restrict__ feats, const float* __restrict__ emb,
                             float* __restrict__ h, int N) {
    int idx = blockIdx.x * blockDim.x + threadIdx.x;   // = n*64 + d
    int n = idx >> 6;
    int d = idx & 63;
    if (n < N) {
        int f = feats[n];
        h[idx] = emb[f * HIDDEN + d];
    }
}

// ---------- SpMM scatter: agg[dst[e]][d] += h[src[e]][d] * nsrc[src[e]] ----------
// one wave (64 lanes) per edge, lane = feature index
__global__ __launch_bounds__(256) void scatter_kernel(const int* __restrict__ src,
                                                      const int* __restrict__ dst,
                                                      const float* __restrict__ h,
                                                      const float* __restrict__ nsrc,
                                                      float* __restrict__ agg, int E) {
    int lane = threadIdx.x & 63;
    int e = blockIdx.x * (blockDim.x >> 6) + (threadIdx.x >> 6);
    if (e < E) {
        int s = src[e];           // wave-uniform
        int d = dst[e];           // wave-uniform
        float v = h[(size_t)s * HIDDEN + lane] * nsrc[s];
        atomicAdd(&agg[(size_t)d * HIDDEN + lane], v);
    }
}

// ---------- per-layer dense: h[n][:] = (agg[n][:] * ndst[n]) @ W + b ----------
// one wave per node; W staged in LDS; row broadcast via shuffle
__global__ __launch_bounds__(256) void gcn_gemm_kernel(const float* __restrict__ agg,
                                                       const float* __restrict__ ndst,
                                                       const float* __restrict__ W,
                                                       const float* __restrict__ b,
                                                       float* __restrict__ h, int N) {
    __shared__ float Ws[HIDDEN * HIDDEN];
    for (int i = threadIdx.x; i < HIDDEN * HIDDEN; i += blockDim.x) Ws[i] = W[i];
    __syncthreads();

    int lane = threadIdx.x & 63;
    int warp = threadIdx.x >> 6;
    int wpb = blockDim.x >> 6;
    float bias = b[lane];

    for (int n = blockIdx.x * wpb + warp; n < N; n += gridDim.x * wpb) {
        float rv = agg[(size_t)n * HIDDEN + lane] * ndst[n];
        float acc = bias;
#pragma unroll
        for (int k = 0; k < HIDDEN; k++) {
            float a = __shfl(rv, k, 64);
            acc = fmaf(a, Ws[k * HIDDEN + lane], acc);
        }
        h[(size_t)n * HIDDEN + lane] = acc;
    }
}

// ---------- sum pooling over sorted graph_ids ----------
__global__ __launch_bounds__(256) void pool_kernel(const int* __restrict__ gids,
                                                   const float* __restrict__ h,
                                                   float* __restrict__ pooled, int N) {
    int lane = threadIdx.x & 63;
    int n = blockIdx.x * (blockDim.x >> 6) + (threadIdx.x >> 6);
    if (n < N) {
        int g = gids[n];
        atomicAdd(&pooled[(size_t)g * HIDDEN + lane], h[(size_t)n * HIDDEN + lane]);
    }
}

// ---------- regression head: out[g] = dot(pooled[g], Wreg) ----------
__global__ __launch_bounds__(256) void head_kernel(const float* __restrict__ pooled,
                                                   const float* __restrict__ Wreg,
                                                   float* __restrict__ out, int G) {
    int lane = threadIdx.x & 63;
    int g = blockIdx.x * (blockDim.x >> 6) + (threadIdx.x >> 6);
    if (g < G) {
        float v = pooled[(size_t)g * HIDDEN + lane] * Wreg[lane];
#pragma unroll
        for (int off = 32; off > 0; off >>= 1) v += __shfl_down(v, off, 64);
        if (lane == 0) out[g] = v;
    }
}

extern "C" void kernel_launch(void* const* d_in, const int* in_sizes, int n_in,
                              void* d_out, int out_size, void* d_ws, size_t ws_size,
                              hipStream_t stream) {
    const int*   feats = (const int*)d_in[0];
    const int*   src   = (const int*)d_in[1];
    const int*   dst   = (const int*)d_in[2];
    const int*   gids  = (const int*)d_in[3];
    // d_in[4] = n_graphs (scalar, fixed at 512)
    const float* emb   = (const float*)d_in[5];
    const float* Ws    = (const float*)d_in[6];
    const float* bs    = (const float*)d_in[7];
    const float* Wreg  = (const float*)d_in[8];
    float* out = (float*)d_out;

    int N = in_sizes[0];
    int E = in_sizes[1];
    const int G = 512;

    float* nsrc   = (float*)d_ws;                    // N
    float* ndst   = nsrc + N;                        // N
    float* h      = ndst + N;                        // N*64
    float* agg    = h + (size_t)N * HIDDEN;          // N*64
    float* pooled = agg + (size_t)N * HIDDEN;        // G*64

    hipMemsetAsync(nsrc, 0, sizeof(float) * 2 * (size_t)N, stream);
    hipMemsetAsync(pooled, 0, sizeof(float) * (size_t)G * HIDDEN, stream);

    degree_kernel<<<2048, 256, 0, stream>>>(src, dst, nsrc, ndst, E);
    norm_kernel<<<(N + 255) / 256, 256, 0, stream>>>(nsrc, ndst, N);
    embed_kernel<<<((size_t)N * HIDDEN + 255) / 256, 256, 0, stream>>>(feats, emb, h, N);

    for (int l = 0; l < 3; l++) {
        hipMemsetAsync(agg, 0, sizeof(float) * (size_t)N * HIDDEN, stream);
        scatter_kernel<<<(E + 3) / 4, 256, 0, stream>>>(src, dst, h, nsrc, agg, E);
        gcn_gemm_kernel<<<1024, 256, 0, stream>>>(agg, ndst, Ws + l * HIDDEN * HIDDEN,
                                                  bs + l * HIDDEN, h, N);
    }

    pool_kernel<<<(N + 3) / 4, 256, 0, stream>>>(gids, h, pooled, N);
    head_kernel<<<(G + 3) / 4, 256, 0, stream>>>(pooled, Wreg, out, G);
}

// Round 2
// 955.704 us; speedup vs baseline: 1.6613x; 1.6613x over previous
//
#include <hip/hip_runtime.h>

#define HIDDEN 64

// ---------- degree counting: float out-degree (for norm) + int in-degree (for CSR) ----------
__global__ void degree_kernel(const int* __restrict__ src, const int* __restrict__ dst,
                              float* __restrict__ outdeg, int* __restrict__ indeg, int E) {
    int e = blockIdx.x * blockDim.x + threadIdx.x;
    if (e < E) {
        atomicAdd(&outdeg[src[e]], 1.0f);
        atomicAdd(&indeg[dst[e]], 1);
    }
}

// nsrc = outdeg^{-1/2}, ndst = indeg^{-1/2}, clamped to min-degree 1
__global__ void norm_kernel(float* __restrict__ nsrc, const int* __restrict__ indeg,
                            float* __restrict__ ndst, int N) {
    int i = blockIdx.x * blockDim.x + threadIdx.x;
    if (i < N) {
        nsrc[i] = rsqrtf(fmaxf(nsrc[i], 1.0f));
        ndst[i] = rsqrtf(fmaxf((float)indeg[i], 1.0f));
    }
}

// ---------- prefix-sum over in-degrees (3-kernel scan) ----------
__global__ void block_sum_kernel(const int* __restrict__ indeg, int* __restrict__ bsum, int N) {
    int t = threadIdx.x;
    int n = blockIdx.x * 256 + t;
    int v = (n < N) ? indeg[n] : 0;
#pragma unroll
    for (int off = 32; off > 0; off >>= 1) v += __shfl_down(v, off, 64);
    __shared__ int s[4];
    if ((t & 63) == 0) s[t >> 6] = v;
    __syncthreads();
    if (t == 0) bsum[blockIdx.x] = s[0] + s[1] + s[2] + s[3];
}

// exclusive scan of block sums in place (single block, B <= 1024)
__global__ void scan_bsum_kernel(int* __restrict__ bsum, int B) {
    __shared__ int tmp[1024];
    int t = threadIdx.x;
    tmp[t] = (t < B) ? bsum[t] : 0;
    __syncthreads();
    for (int off = 1; off < 1024; off <<= 1) {
        int u = (t >= off) ? tmp[t - off] : 0;
        __syncthreads();
        tmp[t] += u;
        __syncthreads();
    }
    if (t < B) bsum[t] = (t > 0) ? tmp[t - 1] : 0;
}

// per-block inclusive scan + block offset -> row_ptr[n+1]; cursor[n] = row start
__global__ void scan_final_kernel(const int* __restrict__ indeg, const int* __restrict__ bsum,
                                  int* __restrict__ cursor, int* __restrict__ row_ptr, int N) {
    __shared__ int tmp[256];
    int t = threadIdx.x;
    int n = blockIdx.x * 256 + t;
    int v = (n < N) ? indeg[n] : 0;
    tmp[t] = v;
    __syncthreads();
    for (int off = 1; off < 256; off <<= 1) {
        int u = (t >= off) ? tmp[t - off] : 0;
        __syncthreads();
        tmp[t] += u;
        __syncthreads();
    }
    if (n < N) {
        int incl = tmp[t] + bsum[blockIdx.x];
        row_ptr[n + 1] = incl;
        cursor[n] = incl - v;   // exclusive = row start
    }
    if (n == 0) row_ptr[0] = 0;
}

// scatter edges into CSR slots
__global__ void fill_csr_kernel(const int* __restrict__ src, const int* __restrict__ dst,
                                int* __restrict__ cursor, int* __restrict__ col, int E) {
    int e = blockIdx.x * blockDim.x + threadIdx.x;
    if (e < E) {
        int d = dst[e];
        int slot = atomicAdd(&cursor[d], 1);
        col[slot] = src[e];
    }
}

// ---------- embedding gather, pre-scaled by nsrc: h[n][d] = emb[feats[n]][d] * nsrc[n] ----------
__global__ void embed_kernel(const int* __restrict__ feats, const float* __restrict__ emb,
                             const float* __restrict__ nsrc, float* __restrict__ h, int N) {
    int idx = blockIdx.x * blockDim.x + threadIdx.x;   // = n*64 + d
    int n = idx >> 6;
    int d = idx & 63;
    if (n < N) {
        int f = feats[n];
        h[idx] = emb[f * HIDDEN + d] * nsrc[n];
    }
}

// ---------- fused gather-SpMM + dense layer ----------
// one wave per dst node, lane = feature. Input rows are pre-scaled by nsrc.
// out = (sum_{s in N(n)} hin[s]) * ndst[n] @ W + b, optionally * nsrc[n] for next layer.
__global__ __launch_bounds__(256) void gather_gemm_kernel(const int* __restrict__ row_ptr,
                                                          const int* __restrict__ col,
                                                          const float* __restrict__ hin,
                                                          const float* __restrict__ ndst,
                                                          const float* __restrict__ nsrc,
                                                          const float* __restrict__ W,
                                                          const float* __restrict__ b,
                                                          float* __restrict__ hout,
                                                          int N, int scale_out) {
    __shared__ float Wsh[HIDDEN * HIDDEN];
    for (int i = threadIdx.x; i < HIDDEN * HIDDEN; i += blockDim.x) Wsh[i] = W[i];
    __syncthreads();

    int lane = threadIdx.x & 63;
    int warp = threadIdx.x >> 6;
    int n = blockIdx.x * 4 + warp;
    if (n >= N) return;

    int beg = row_ptr[n];
    int end = row_ptr[n + 1];
    float acc = 0.0f;
    for (int base = beg; base < end; base += 64) {
        int j = base + lane;
        int myc = (j < end) ? col[j] : 0;        // coalesced chunk of column indices
        int m = end - base; if (m > 64) m = 64;
        for (int t = 0; t < m; t++) {
            int s = __shfl(myc, t, 64);          // broadcast edge source
            acc += hin[(size_t)s * HIDDEN + lane];
        }
    }
    float rv = acc * ndst[n];
    float o = b[lane];
#pragma unroll
    for (int k = 0; k < HIDDEN; k++) {
        o = fmaf(__shfl(rv, k, 64), Wsh[k * HIDDEN + lane], o);
    }
    if (scale_out) o *= nsrc[n];
    hout[(size_t)n * HIDDEN + lane] = o;
}

// ---------- sum pooling ----------
__global__ __launch_bounds__(256) void pool_kernel(const int* __restrict__ gids,
                                                   const float* __restrict__ h,
                                                   float* __restrict__ pooled, int N) {
    int lane = threadIdx.x & 63;
    int n = blockIdx.x * (blockDim.x >> 6) + (threadIdx.x >> 6);
    if (n < N) {
        int g = gids[n];
        atomicAdd(&pooled[(size_t)g * HIDDEN + lane], h[(size_t)n * HIDDEN + lane]);
    }
}

// ---------- regression head ----------
__global__ __launch_bounds__(256) void head_kernel(const float* __restrict__ pooled,
                                                   const float* __restrict__ Wreg,
                                                   float* __restrict__ out, int G) {
    int lane = threadIdx.x & 63;
    int g = blockIdx.x * (blockDim.x >> 6) + (threadIdx.x >> 6);
    if (g < G) {
        float v = pooled[(size_t)g * HIDDEN + lane] * Wreg[lane];
#pragma unroll
        for (int off = 32; off > 0; off >>= 1) v += __shfl_down(v, off, 64);
        if (lane == 0) out[g] = v;
    }
}

extern "C" void kernel_launch(void* const* d_in, const int* in_sizes, int n_in,
                              void* d_out, int out_size, void* d_ws, size_t ws_size,
                              hipStream_t stream) {
    const int*   feats = (const int*)d_in[0];
    const int*   src   = (const int*)d_in[1];
    const int*   dst   = (const int*)d_in[2];
    const int*   gids  = (const int*)d_in[3];
    const float* emb   = (const float*)d_in[5];
    const float* Ws    = (const float*)d_in[6];
    const float* bs    = (const float*)d_in[7];
    const float* Wreg  = (const float*)d_in[8];
    float* out = (float*)d_out;

    int N = in_sizes[0];
    int E = in_sizes[1];
    const int G = 512;
    int NB = (N + 255) / 256;   // scan blocks (391 for N=100000)

    // workspace layout (ints/floats are both 4B)
    char* p = (char*)d_ws;
    float* nsrc    = (float*)p;  p += (size_t)N * 4;        // zeroed (counts first)
    int*   indeg   = (int*)p;    p += (size_t)N * 4;        // zeroed
    float* ndst    = (float*)p;  p += (size_t)N * 4;
    int*   cursor  = (int*)p;    p += (size_t)N * 4;
    int*   row_ptr = (int*)p;    p += (size_t)(N + 1) * 4;
    int*   bsum    = (int*)p;    p += 1024 * 4;
    int*   col     = (int*)p;    p += (size_t)E * 4;
    p = (char*)(((uintptr_t)p + 15) & ~(uintptr_t)15);
    float* h0      = (float*)p;  p += (size_t)N * HIDDEN * 4;
    float* h1      = (float*)p;  p += (size_t)N * HIDDEN * 4;
    float* pooled  = (float*)p;  p += (size_t)G * HIDDEN * 4;

    hipMemsetAsync(nsrc, 0, (size_t)N * 8, stream);                  // nsrc + indeg
    hipMemsetAsync(pooled, 0, (size_t)G * HIDDEN * 4, stream);

    degree_kernel<<<(E + 255) / 256, 256, 0, stream>>>(src, dst, nsrc, indeg, E);
    norm_kernel<<<NB, 256, 0, stream>>>(nsrc, indeg, ndst, N);

    // CSR build
    block_sum_kernel<<<NB, 256, 0, stream>>>(indeg, bsum, N);
    scan_bsum_kernel<<<1, 1024, 0, stream>>>(bsum, NB);
    scan_final_kernel<<<NB, 256, 0, stream>>>(indeg, bsum, cursor, row_ptr, N);
    fill_csr_kernel<<<(E + 255) / 256, 256, 0, stream>>>(src, dst, cursor, col, E);

    // h0 = emb[feats] * nsrc
    embed_kernel<<<((size_t)N * HIDDEN + 255) / 256, 256, 0, stream>>>(feats, emb, nsrc, h0, N);

    // 3 fused SpMM+dense layers, ping-pong h0/h1; layers 0,1 pre-scale output by nsrc
    gather_gemm_kernel<<<(N + 3) / 4, 256, 0, stream>>>(row_ptr, col, h0, ndst, nsrc,
                                                        Ws + 0 * HIDDEN * HIDDEN, bs + 0 * HIDDEN,
                                                        h1, N, 1);
    gather_gemm_kernel<<<(N + 3) / 4, 256, 0, stream>>>(row_ptr, col, h1, ndst, nsrc,
                                                        Ws + 1 * HIDDEN * HIDDEN, bs + 1 * HIDDEN,
                                                        h0, N, 1);
    gather_gemm_kernel<<<(N + 3) / 4, 256, 0, stream>>>(row_ptr, col, h0, ndst, nsrc,
                                                        Ws + 2 * HIDDEN * HIDDEN, bs + 2 * HIDDEN,
                                                        h1, N, 0);

    pool_kernel<<<(N + 3) / 4, 256, 0, stream>>>(gids, h1, pooled, N);
    head_kernel<<<(G + 3) / 4, 256, 0, stream>>>(pooled, Wreg, out, G);
}